// Round 3
// baseline (240.121 us; speedup 1.0000x reference)
//
#include <hip/hip_runtime.h>
#include <hip/hip_bf16.h>

// Problem constants
#define NUM_EXPERT 8
#define IN_FEAT    1024
#define HIDDEN_FEAT 4096
#define OUT_FEAT   1024
#define BATCH      2048

#define BM 128
#define BK 64
#define MAX_RBLK 24   // sum_e ceil(c_e/128) <= 8 + 2048/128 = 24

typedef __attribute__((ext_vector_type(8))) short  bf16x8;
typedef __attribute__((ext_vector_type(4))) short  bf16x4;
typedef __attribute__((ext_vector_type(4))) float  f32x4;

__device__ inline short f2bf_rne(float f) {
    unsigned u = __builtin_bit_cast(unsigned, f);
    u += 0x7FFF + ((u >> 16) & 1);
    return (short)(u >> 16);
}

// ---------------------------------------------------------------------------
// prep: histogram gate, exclusive scan, build row-block table + permutation.
// hdr layout (ints): [0]=n_blocks; [16 + 4*i .. ] = {expert, row_start, row_end};
// [256..256+2048) = perm (gathered row -> original token)
//
// gate declared int64 in the reference; harness may push int32 or int64.
// Runtime probe: if all odd int32 words of the first 2048 are zero -> int64.
// ---------------------------------------------------------------------------
__global__ __launch_bounds__(256) void prep_kernel(const int* __restrict__ gate32,
                                                   int* __restrict__ hdr) {
    __shared__ int cnt[NUM_EXPERT];
    __shared__ int cur[NUM_EXPERT];
    __shared__ int odd_nonzero;
    int tid = threadIdx.x;
    if (tid < NUM_EXPERT) cnt[tid] = 0;
    if (tid == 0) odd_nonzero = 0;
    __syncthreads();

    int acc = 0;
    for (int t = tid; t < BATCH / 2; t += 256) acc |= gate32[2 * t + 1];
    if (acc) atomicOr(&odd_nonzero, 1);
    __syncthreads();
    const int is64 = (odd_nonzero == 0);

    for (int t = tid; t < BATCH; t += 256) {
        int g = is64 ? gate32[2 * t] : gate32[t];
        atomicAdd(&cnt[g], 1);
    }
    __syncthreads();
    if (tid == 0) {
        int o = 0, nb = 0;
        for (int e = 0; e < NUM_EXPERT; ++e) {
            cur[e] = o;
            int c = cnt[e];
            int rb = (c + BM - 1) / BM;
            for (int j = 0; j < rb; ++j) {
                hdr[16 + nb * 4 + 0] = e;
                hdr[16 + nb * 4 + 1] = o + j * BM;
                int re = o + j * BM + BM;
                if (re > o + c) re = o + c;
                hdr[16 + nb * 4 + 2] = re;
                ++nb;
            }
            o += c;
        }
        hdr[0] = nb;
    }
    __syncthreads();
    for (int t = tid; t < BATCH; t += 256) {
        int g = is64 ? gate32[2 * t] : gate32[t];
        int d = atomicAdd(&cur[g], 1);
        hdr[256 + d] = t;
    }
}

// ---------------------------------------------------------------------------
// gather: Xg[r][:] = bf16(inp[perm[r]][:])   one row per block
// ---------------------------------------------------------------------------
__global__ __launch_bounds__(256) void gather_kernel(const float* __restrict__ inp,
                                                     const int* __restrict__ perm,
                                                     short* __restrict__ Xg) {
    int r = blockIdx.x;
    int t = perm[r];
    const f32x4* src = (const f32x4*)(inp + (size_t)t * IN_FEAT);
    f32x4 f = src[threadIdx.x];
    bf16x4 v;
    v[0] = f2bf_rne(f[0]); v[1] = f2bf_rne(f[1]);
    v[2] = f2bf_rne(f[2]); v[3] = f2bf_rne(f[3]);
    *(bf16x4*)(Xg + (size_t)r * IN_FEAT + threadIdx.x * 4) = v;
}

// ---------------------------------------------------------------------------
// Tiled MFMA GEMM: C[r][n] = sum_k A[r][k] * W[e][n][k]
// A: bf16 [*, lda] gathered rows.  W: fp32 [E][N][K] (converted inline).
// STORE_F32=false -> store bf16 to Cbf (hidden); true -> scatter fp32 to Cf
// at row perm[r].
// ---------------------------------------------------------------------------
template <int BN_, bool STORE_F32>
__global__ __launch_bounds__(256) void gemm_kernel(
    const short* __restrict__ A, int lda,
    const float* __restrict__ W, int N, int K,
    short* __restrict__ Cbf, float* __restrict__ Cf, int ldc,
    const int* __restrict__ hdr) {

    int nb = hdr[0];
    int ib = blockIdx.y;
    if (ib >= nb) return;
    int e  = hdr[16 + ib * 4 + 0];
    int rs = hdr[16 + ib * 4 + 1];
    int re = hdr[16 + ib * 4 + 2];
    const int* perm = hdr + 256;

    int n0 = blockIdx.x * BN_;
    const float* Wb = W + (size_t)e * N * K;

    __shared__ short As[BM * BK];
    __shared__ short Bs[BN_ * BK];

    int tid  = threadIdx.x;
    int lane = tid & 63;
    int w    = tid >> 6;
    int wr   = w >> 1, wc = w & 1;      // 2x2 wave grid
    int lo   = lane & 15, hi = lane >> 4;

    constexpr int NF = BN_ / 32;        // 16-col frags per wave in N
    f32x4 acc[4][NF];
#pragma unroll
    for (int m = 0; m < 4; ++m)
#pragma unroll
        for (int n = 0; n < NF; ++n) acc[m][n] = (f32x4){0.f, 0.f, 0.f, 0.f};

    for (int k0 = 0; k0 < K; k0 += BK) {
        // ---- stage A (bf16, zero-pad invalid rows), XOR-swizzled LDS ----
#pragma unroll
        for (int it = 0; it < (BM * BK) / 2048; ++it) {
            int linear = it * 2048 + tid * 8;
            int row = linear >> 6, col = linear & 63;
            bf16x8 v = {0, 0, 0, 0, 0, 0, 0, 0};
            int grow = rs + row;
            if (grow < re)
                v = *(const bf16x8*)(A + (size_t)grow * lda + k0 + col);
            int c = (col >> 3) ^ (row & 7);
            *(bf16x8*)(As + row * 64 + c * 8) = v;
        }
        // ---- stage B (fp32 -> bf16 inline), XOR-swizzled LDS ----
#pragma unroll
        for (int it = 0; it < (BN_ * BK) / 2048; ++it) {
            int linear = it * 2048 + tid * 8;
            int row = linear >> 6, col = linear & 63;
            const float* src = Wb + (size_t)(n0 + row) * K + k0 + col;
            f32x4 f0 = *(const f32x4*)src;
            f32x4 f1 = *(const f32x4*)(src + 4);   // FIXED: next 4 floats
            bf16x8 v;
            v[0] = f2bf_rne(f0[0]); v[1] = f2bf_rne(f0[1]);
            v[2] = f2bf_rne(f0[2]); v[3] = f2bf_rne(f0[3]);
            v[4] = f2bf_rne(f1[0]); v[5] = f2bf_rne(f1[1]);
            v[6] = f2bf_rne(f1[2]); v[7] = f2bf_rne(f1[3]);
            int c = (col >> 3) ^ (row & 7);
            *(bf16x8*)(Bs + row * 64 + c * 8) = v;
        }
        __syncthreads();

        // ---- MFMA over the two 32-wide K chunks ----
#pragma unroll
        for (int kk = 0; kk < 2; ++kk) {
            int cbase = kk * 4 + hi;    // 8-short chunk index within row
            bf16x8 af[4], bfr[NF];
#pragma unroll
            for (int m = 0; m < 4; ++m) {
                int row = wr * 64 + m * 16 + lo;
                int c = cbase ^ (row & 7);
                af[m] = *(const bf16x8*)(As + row * 64 + c * 8);
            }
#pragma unroll
            for (int n = 0; n < NF; ++n) {
                int row = wc * (BN_ / 2) + n * 16 + lo;
                int c = cbase ^ (row & 7);
                bfr[n] = *(const bf16x8*)(Bs + row * 64 + c * 8);
            }
#pragma unroll
            for (int m = 0; m < 4; ++m)
#pragma unroll
                for (int n = 0; n < NF; ++n)
                    acc[m][n] = __builtin_amdgcn_mfma_f32_16x16x32_bf16(
                        af[m], bfr[n], acc[m][n], 0, 0, 0);
        }
        __syncthreads();
    }

    // ---- epilogue: D frag mapping col=lane&15, row=(lane>>4)*4+reg ----
#pragma unroll
    for (int m = 0; m < 4; ++m) {
#pragma unroll
        for (int rg = 0; rg < 4; ++rg) {
            int brow = wr * 64 + m * 16 + hi * 4 + rg;
            int grow = rs + brow;
            if (grow < re) {
                if (STORE_F32) {
                    int token = perm[grow];
                    float* dst = Cf + (size_t)token * ldc;
#pragma unroll
                    for (int n = 0; n < NF; ++n)
                        dst[n0 + wc * (BN_ / 2) + n * 16 + lo] = acc[m][n][rg];
                } else {
                    short* dst = Cbf + (size_t)grow * ldc;
#pragma unroll
                    for (int n = 0; n < NF; ++n)
                        dst[n0 + wc * (BN_ / 2) + n * 16 + lo] =
                            f2bf_rne(acc[m][n][rg]);
                }
            }
        }
    }
}

// ---------------------------------------------------------------------------
extern "C" void kernel_launch(void* const* d_in, const int* in_sizes, int n_in,
                              void* d_out, int out_size, void* d_ws, size_t ws_size,
                              hipStream_t stream) {
    const float* inp  = (const float*)d_in[0];
    const int*   gate = (const int*)d_in[1];
    const float* w1   = (const float*)d_in[2];
    const float* w2   = (const float*)d_in[3];
    float*       out  = (float*)d_out;

    int*   hdr = (int*)d_ws;
    short* Xg  = (short*)((char*)d_ws + 16384);
    short* Hid = (short*)((char*)d_ws + 16384 + (size_t)BATCH * IN_FEAT * 2);

    prep_kernel<<<1, 256, 0, stream>>>(gate, hdr);
    gather_kernel<<<BATCH, 256, 0, stream>>>(inp, hdr + 256, Xg);

    // GEMM1: [B,1024] x W1[e][4096,1024] -> Hid bf16 [B,4096]
    gemm_kernel<128, false><<<dim3(HIDDEN_FEAT / 128, MAX_RBLK), 256, 0, stream>>>(
        Xg, IN_FEAT, w1, HIDDEN_FEAT, IN_FEAT, Hid, nullptr, HIDDEN_FEAT, hdr);

    // GEMM2: [B,4096] x W2[e][1024,4096] -> out fp32 scattered to token rows
    gemm_kernel<64, true><<<dim3(OUT_FEAT / 64, MAX_RBLK), 256, 0, stream>>>(
        Hid, HIDDEN_FEAT, w2, OUT_FEAT, HIDDEN_FEAT, nullptr, out, OUT_FEAT, hdr);
}

// Round 4
// 134.367 us; speedup vs baseline: 1.7871x; 1.7871x over previous
//
#include <hip/hip_runtime.h>
#include <hip/hip_bf16.h>

// Problem constants
#define NUM_EXPERT 8
#define IN_FEAT    1024
#define HIDDEN_FEAT 4096
#define OUT_FEAT   1024
#define BATCH      2048

#define BM 128
#define BK 64
#define MAX_RBLK 24   // sum_e ceil(c_e/128) <= 16 + 8 = 24
#define KSPLIT2 4     // split-K factor for GEMM2

// ws layout (slack rows so unguarded A-tile loads stay in-bounds)
#define XG_ROWS   (BATCH + BM)
#define HDR_BYTES 16384
#define XG_BYTES  ((size_t)XG_ROWS * IN_FEAT * 2)
#define HID_BYTES ((size_t)XG_ROWS * HIDDEN_FEAT * 2)
#define PART_OFF  (HDR_BYTES + XG_BYTES + HID_BYTES)
#define PART_BYTES ((size_t)KSPLIT2 * BATCH * OUT_FEAT * 4)
#define WS_NEED   (PART_OFF + PART_BYTES)

typedef __attribute__((ext_vector_type(8))) short  bf16x8;
typedef __attribute__((ext_vector_type(4))) short  bf16x4;
typedef __attribute__((ext_vector_type(4))) float  f32x4;

__device__ inline short f2bf_rne(float f) {
    unsigned u = __builtin_bit_cast(unsigned, f);
    u += 0x7FFF + ((u >> 16) & 1);
    return (short)(u >> 16);
}

// ---------------------------------------------------------------------------
// prep: histogram gate, scan, row-block table + permutation.
// hdr ints: [0]=n_blocks; [16+4i..]={expert,row_start,row_end}; [256..]=perm
// gate dtype probe: all odd int32 words zero -> int64 layout.
// ---------------------------------------------------------------------------
__global__ __launch_bounds__(256) void prep_kernel(const int* __restrict__ gate32,
                                                   int* __restrict__ hdr) {
    __shared__ int cnt[NUM_EXPERT];
    __shared__ int cur[NUM_EXPERT];
    __shared__ int odd_nonzero;
    int tid = threadIdx.x;
    if (tid < NUM_EXPERT) cnt[tid] = 0;
    if (tid == 0) odd_nonzero = 0;
    __syncthreads();

    int acc = 0;
    for (int t = tid; t < BATCH / 2; t += 256) acc |= gate32[2 * t + 1];
    if (acc) atomicOr(&odd_nonzero, 1);
    __syncthreads();
    const int is64 = (odd_nonzero == 0);

    for (int t = tid; t < BATCH; t += 256) {
        int g = is64 ? gate32[2 * t] : gate32[t];
        atomicAdd(&cnt[g], 1);
    }
    __syncthreads();
    if (tid == 0) {
        int o = 0, nb = 0;
        for (int e = 0; e < NUM_EXPERT; ++e) {
            cur[e] = o;
            int c = cnt[e];
            int rb = (c + BM - 1) / BM;
            for (int j = 0; j < rb; ++j) {
                hdr[16 + nb * 4 + 0] = e;
                hdr[16 + nb * 4 + 1] = o + j * BM;
                int re = o + j * BM + BM;
                if (re > o + c) re = o + c;
                hdr[16 + nb * 4 + 2] = re;
                ++nb;
            }
            o += c;
        }
        hdr[0] = nb;
    }
    __syncthreads();
    for (int t = tid; t < BATCH; t += 256) {
        int g = is64 ? gate32[2 * t] : gate32[t];
        int d = atomicAdd(&cur[g], 1);
        hdr[256 + d] = t;
    }
}

// ---------------------------------------------------------------------------
// gather: Xg[r][:] = bf16(inp[perm[r]][:])
// ---------------------------------------------------------------------------
__global__ __launch_bounds__(256) void gather_kernel(const float* __restrict__ inp,
                                                     const int* __restrict__ perm,
                                                     short* __restrict__ Xg) {
    int r = blockIdx.x;
    int t = perm[r];
    const f32x4* src = (const f32x4*)(inp + (size_t)t * IN_FEAT);
    f32x4 f = src[threadIdx.x];
    bf16x4 v;
    v[0] = f2bf_rne(f[0]); v[1] = f2bf_rne(f[1]);
    v[2] = f2bf_rne(f[2]); v[3] = f2bf_rne(f[3]);
    *(bf16x4*)(Xg + (size_t)r * IN_FEAT + threadIdx.x * 4) = v;
}

// ---------------------------------------------------------------------------
// Pipelined MFMA GEMM: C[r][n] = sum_k A[r][k] * W[e][n][k]
// A bf16 [*,lda]; W fp32 [E][N][K] converted inline.
// MODE 0: store bf16 at gathered row (Cbf).
// MODE 1: store fp32 partial at partials + z*B*O (z=blockIdx.z, K split).
// MODE 2: store fp32 scattered to Cf[perm[r]].
// T14 pipeline: next tile's global loads issued during current tile's MFMA.
// ---------------------------------------------------------------------------
template <int BN_, int MODE, int KSPLIT>
__global__ __launch_bounds__(256) void gemm_kernel(
    const short* __restrict__ A, int lda,
    const float* __restrict__ W, int N, int K,
    short* __restrict__ Cbf, float* __restrict__ Cf, int ldc,
    const int* __restrict__ hdr) {

    int nb = hdr[0];
    int ib = blockIdx.y;
    if (ib >= nb) return;
    int e  = hdr[16 + ib * 4 + 0];
    int rs = hdr[16 + ib * 4 + 1];
    int re = hdr[16 + ib * 4 + 2];
    const int* perm = hdr + 256;

    int n0 = blockIdx.x * BN_;
    const float* Wb = W + (size_t)e * N * K;

    __shared__ short As[BM * BK];
    __shared__ short Bs[BN_ * BK];

    int tid  = threadIdx.x;
    int lane = tid & 63;
    int w    = tid >> 6;
    int wr   = w >> 1, wc = w & 1;      // 2x2 wave grid
    int lo   = lane & 15, hi = lane >> 4;

    constexpr int NF  = BN_ / 32;       // 16-col frags per wave in N
    constexpr int BIT = (BN_ * BK) / 2048;

    f32x4 acc[4][NF];
#pragma unroll
    for (int m = 0; m < 4; ++m)
#pragma unroll
        for (int n = 0; n < NF; ++n) acc[m][n] = (f32x4){0.f, 0.f, 0.f, 0.f};

    // per-thread staging geometry: chunk row = tid>>3 (+32/it), col = (tid&7)*8
    const int arow  = tid >> 3;
    const int acol  = (tid & 7) * 8;
    const int cbase = tid & 7;
    const int swz   = cbase ^ (arow & 7);   // (arow+32it)&7 == arow&7
    const short* Abase = A  + (size_t)(rs + arow) * lda + acol;
    const float* Bbase = Wb + (size_t)(n0 + arow) * K   + acol;

    const int kb = (KSPLIT > 1) ? (int)blockIdx.z * (K / KSPLIT) : 0;
    const int nt = (K / KSPLIT) / BK;

    bf16x8 ra[4];
    f32x4  rb[BIT][2];

    auto loadA = [&](int k0) {
#pragma unroll
        for (int it = 0; it < 4; ++it)
            ra[it] = *(const bf16x8*)(Abase + (size_t)(it * 32) * lda + k0);
    };
    auto loadB = [&](int k0) {
#pragma unroll
        for (int it = 0; it < BIT; ++it) {
            const float* s = Bbase + (size_t)(it * 32) * K + k0;
            rb[it][0] = *(const f32x4*)s;
            rb[it][1] = *(const f32x4*)(s + 4);
        }
    };
    auto storeLDS = [&]() {
#pragma unroll
        for (int it = 0; it < 4; ++it)
            *(bf16x8*)(As + (arow + it * 32) * 64 + swz * 8) = ra[it];
#pragma unroll
        for (int it = 0; it < BIT; ++it) {
            bf16x8 v;
            v[0] = f2bf_rne(rb[it][0][0]); v[1] = f2bf_rne(rb[it][0][1]);
            v[2] = f2bf_rne(rb[it][0][2]); v[3] = f2bf_rne(rb[it][0][3]);
            v[4] = f2bf_rne(rb[it][1][0]); v[5] = f2bf_rne(rb[it][1][1]);
            v[6] = f2bf_rne(rb[it][1][2]); v[7] = f2bf_rne(rb[it][1][3]);
            *(bf16x8*)(Bs + (arow + it * 32) * 64 + swz * 8) = v;
        }
    };

    loadA(kb);
    loadB(kb);

    for (int kt = 0; kt < nt; ++kt) {
        storeLDS();
        __syncthreads();
        if (kt + 1 < nt) {              // prefetch next tile during compute
            loadA(kb + (kt + 1) * BK);
            loadB(kb + (kt + 1) * BK);
        }
#pragma unroll
        for (int kk = 0; kk < 2; ++kk) {
            int cb = kk * 4 + hi;       // 8-short chunk index within row
            bf16x8 af[4], bfr[NF];
#pragma unroll
            for (int m = 0; m < 4; ++m) {
                int row = wr * 64 + m * 16 + lo;
                int c = cb ^ (row & 7);
                af[m] = *(const bf16x8*)(As + row * 64 + c * 8);
            }
#pragma unroll
            for (int n = 0; n < NF; ++n) {
                int row = wc * (BN_ / 2) + n * 16 + lo;
                int c = cb ^ (row & 7);
                bfr[n] = *(const bf16x8*)(Bs + row * 64 + c * 8);
            }
#pragma unroll
            for (int m = 0; m < 4; ++m)
#pragma unroll
                for (int n = 0; n < NF; ++n)
                    acc[m][n] = __builtin_amdgcn_mfma_f32_16x16x32_bf16(
                        af[m], bfr[n], acc[m][n], 0, 0, 0);
        }
        __syncthreads();
    }

    // epilogue: D frag mapping col=lane&15, row=(lane>>4)*4+reg
#pragma unroll
    for (int m = 0; m < 4; ++m) {
#pragma unroll
        for (int rg = 0; rg < 4; ++rg) {
            int brow = wr * 64 + m * 16 + hi * 4 + rg;
            int grow = rs + brow;
            if (grow < re) {
                if constexpr (MODE == 0) {
                    short* dst = Cbf + (size_t)grow * ldc;
#pragma unroll
                    for (int n = 0; n < NF; ++n)
                        dst[n0 + wc * (BN_ / 2) + n * 16 + lo] =
                            f2bf_rne(acc[m][n][rg]);
                } else if constexpr (MODE == 1) {
                    float* dst = Cf + (size_t)blockIdx.z * (BATCH * OUT_FEAT)
                                    + (size_t)grow * ldc;
#pragma unroll
                    for (int n = 0; n < NF; ++n)
                        dst[n0 + wc * (BN_ / 2) + n * 16 + lo] = acc[m][n][rg];
                } else {
                    int token = perm[grow];
                    float* dst = Cf + (size_t)token * ldc;
#pragma unroll
                    for (int n = 0; n < NF; ++n)
                        dst[n0 + wc * (BN_ / 2) + n * 16 + lo] = acc[m][n][rg];
                }
            }
        }
    }
}

// ---------------------------------------------------------------------------
// reduce split-K partials (fixed z order -> deterministic) + scatter to token
// ---------------------------------------------------------------------------
__global__ __launch_bounds__(256) void reduce_kernel(const float* __restrict__ part,
                                                     const int* __restrict__ perm,
                                                     float* __restrict__ out) {
    int r = blockIdx.x;
    const float* p = part + (size_t)r * OUT_FEAT + threadIdx.x * 4;
    f32x4 s = *(const f32x4*)p;
#pragma unroll
    for (int z = 1; z < KSPLIT2; ++z)
        s += *(const f32x4*)(p + (size_t)z * BATCH * OUT_FEAT);
    int token = perm[r];
    *(f32x4*)(out + (size_t)token * OUT_FEAT + threadIdx.x * 4) = s;
}

// ---------------------------------------------------------------------------
extern "C" void kernel_launch(void* const* d_in, const int* in_sizes, int n_in,
                              void* d_out, int out_size, void* d_ws, size_t ws_size,
                              hipStream_t stream) {
    const float* inp  = (const float*)d_in[0];
    const int*   gate = (const int*)d_in[1];
    const float* w1   = (const float*)d_in[2];
    const float* w2   = (const float*)d_in[3];
    float*       out  = (float*)d_out;

    int*   hdr  = (int*)d_ws;
    short* Xg   = (short*)((char*)d_ws + HDR_BYTES);
    short* Hid  = (short*)((char*)d_ws + HDR_BYTES + XG_BYTES);
    float* part = (float*)((char*)d_ws + PART_OFF);

    prep_kernel<<<1, 256, 0, stream>>>(gate, hdr);
    gather_kernel<<<BATCH, 256, 0, stream>>>(inp, hdr + 256, Xg);

    // GEMM1: [B,1024] x W1[e][4096,1024]^T -> Hid bf16 [B,4096]
    gemm_kernel<128, 0, 1><<<dim3(HIDDEN_FEAT / 128, MAX_RBLK), 256, 0, stream>>>(
        Xg, IN_FEAT, w1, HIDDEN_FEAT, IN_FEAT, Hid, nullptr, HIDDEN_FEAT, hdr);

    if (ws_size >= WS_NEED) {
        // GEMM2 split-K=4: fp32 partials, then deterministic reduce + scatter
        gemm_kernel<64, 1, KSPLIT2>
            <<<dim3(OUT_FEAT / 64, MAX_RBLK, KSPLIT2), 256, 0, stream>>>(
                Hid, HIDDEN_FEAT, w2, OUT_FEAT, HIDDEN_FEAT, nullptr, part,
                OUT_FEAT, hdr);
        reduce_kernel<<<BATCH, 256, 0, stream>>>(part, hdr + 256, out);
    } else {
        // fallback: direct scatter, no split
        gemm_kernel<64, 2, 1><<<dim3(OUT_FEAT / 64, MAX_RBLK), 256, 0, stream>>>(
            Hid, HIDDEN_FEAT, w2, OUT_FEAT, HIDDEN_FEAT, nullptr, out,
            OUT_FEAT, hdr);
    }
}